// Round 10
// baseline (2513.943 us; speedup 1.0000x reference)
//
#include <hip/hip_runtime.h>

// Problem: B,C,H,W = 16,256,32,32; K=16384. N = 16384 rows.
#define KCODES 16384
#define NPOS   16384
#define CAP    16
#define MARGIN 1e-4f   // >= 2 d-grid steps (2*3.05e-5) + split-bf16 error (6e-7)

// ws float offsets (total ~51.1 MB)
#define OFF_XT    0           // [N][256] fp32 packed x ("flat")
#define OFF_XHP   4194304     // bf16 plane xh [N][256]
#define OFF_XLP   6291456     // bf16 plane xl
#define OFF_WHP   8388608     // bf16 plane wh [K][256]
#define OFF_WLP   10485760    // bf16 plane wl
#define OFF_WN    12582912    // [K]  |w|^2 (np-pairwise exact)
#define OFF_NS1   12599296    // [N] -|f|^2
#define OFF_IDX   12615680    // [N] final argmax (int)
#define OFF_CAND  12632064    // u16 [N][16] candidate codes
#define OFF_CCNT  12763136    // [N] candidate counts (int)
#define OFF_SUMS  12779520    // [2] {sum mask, sum masked err^2}

#define OUT_LOSS  4194304
#define OUT_IND   4194305

#define AS1 __attribute__((address_space(1)))
#define AS3 __attribute__((address_space(3)))

typedef short bf16x8 __attribute__((ext_vector_type(8)));   // 8 bf16 = 4 VGPRs
typedef float f32x4  __attribute__((ext_vector_type(4)));

__device__ inline unsigned short bf16rn(float f) {
    unsigned u = __float_as_uint(f);
    return (unsigned short)((u + 0x7FFFu + ((u >> 16) & 1u)) >> 16);
}
__device__ inline float bf2f(unsigned short h) {
    return __uint_as_float(((unsigned)h) << 16);
}
__device__ inline unsigned monof(float f) {   // monotone float->uint key
    unsigned u = __float_as_uint(f);
    return (u & 0x80000000u) ? ~u : (u | 0x80000000u);
}
__device__ inline float unmonof(unsigned k) {
    unsigned u = (k & 0x80000000u) ? (k & 0x7fffffffu) : ~k;
    return __uint_as_float(u);
}

// ---------- K1a: pack x (B,C,HW) -> xt[N][256] via LDS tile transpose ----------
__global__ void k1a_pack_x(const float* __restrict__ x, float* __restrict__ xt)
{
    __shared__ float t[32][33];
    const int p0 = blockIdx.x * 32, c0 = blockIdx.y * 32, b = blockIdx.z;
    const int tx = threadIdx.x, ty = threadIdx.y;   // 32 x 8
#pragma unroll
    for (int i = 0; i < 4; ++i) {
        int cl = ty + i * 8;
        t[cl][tx] = x[(b * 256 + c0 + cl) * 1024 + p0 + tx];
    }
    __syncthreads();
#pragma unroll
    for (int i = 0; i < 4; ++i) {
        int pl = ty + i * 8;
        xt[(b * 1024 + p0 + pl) * 256 + c0 + tx] = t[tx][pl];
    }
}

// ---------- Ksplit: fp32 row-major -> (bf16 hi plane, bf16 lo plane) ----------
__global__ void k_split(const float4* __restrict__ src4,
                        ushort4* __restrict__ hp, ushort4* __restrict__ lp)
{
    const int i = blockIdx.x * 256 + threadIdx.x;
    const float4 v = src4[i];
    ushort4 h, l;
    h.x = bf16rn(v.x); l.x = bf16rn(v.x - bf2f(h.x));
    h.y = bf16rn(v.y); l.y = bf16rn(v.y - bf2f(h.y));
    h.z = bf16rn(v.z); l.z = bf16rn(v.z - bf2f(h.z));
    h.w = bf16rn(v.w); l.w = bf16rn(v.w - bf2f(h.w));
    hp[i] = h; lp[i] = l;
}

// ---------- Krn: numpy-pairwise fp32 sum of squares per 256-elem row ----------
__global__ void k_rownorm(const float4* __restrict__ src4, float* __restrict__ out,
                          float sign)
{
    __shared__ float4 rows[32 * 64];
    const int tid = threadIdx.x;
    const int r0 = blockIdx.x * 32;
#pragma unroll
    for (int i = 0; i < 8; ++i) rows[tid + 256 * i] = src4[r0 * 64 + tid + 256 * i];
    __syncthreads();
    const int rl = tid >> 3, j = tid & 7;
    const float* qp = (const float*)&rows[rl * 64];
    float h[2];
#pragma unroll
    for (int half = 0; half < 2; ++half) {
        const float* p = qp + half * 128;
        float x = p[j];
        float r = __fmul_rn(x, x);
#pragma unroll
        for (int i = 1; i < 16; ++i) {
            float y = p[8 * i + j];
            r = __fadd_rn(r, __fmul_rn(y, y));
        }
        float t = __fadd_rn(r, __shfl_xor(r, 1));
        t = __fadd_rn(t, __shfl_xor(t, 2));
        t = __fadd_rn(t, __shfl_xor(t, 4));
        h[half] = t;
    }
    if (j == 0) out[r0 + rl] = sign * __fadd_rn(h[0], h[1]);
}

// ---------- K2: split-bf16 MFMA GEMM + approx-d argmax candidate collection ----
__global__ __launch_bounds__(256, 2) void k2_mfma(
    const unsigned short* __restrict__ xhp, const unsigned short* __restrict__ xlp,
    const unsigned short* __restrict__ whp, const unsigned short* __restrict__ wlp,
    const float* __restrict__ wn, const float* __restrict__ ns1,
    unsigned short* __restrict__ candk, int* __restrict__ candc)
{
    __shared__ __align__(16) unsigned short As[16384]; // 32KB: slot16 = half*1024 + cc*32 + row
    __shared__ __align__(16) unsigned short Bs[16384]; // 32KB: slot16 = half*1024 + code*4 + q'
    __shared__ unsigned rowmaxU[32];
    __shared__ int ccnt[32];
    __shared__ unsigned short ck[32][CAP];

    const int tid  = threadIdx.x;
    const int lane = tid & 63;
    const int w    = tid >> 6;     // wave 0..3 -> code sub-range
    const int q    = lane >> 4;    // k-chunk quad
    const int nn   = lane & 15;    // A-row / B-col / D-col position
    const int rowBase = blockIdx.x * 32;

    // stage A once: 2048 slots of 16B
#pragma unroll
    for (int i = 0; i < 8; ++i) {
        const int slot = i * 256 + tid;
        const int half = slot >> 10, cc = (slot >> 5) & 31, row = slot & 31;
        const unsigned short* src = (half ? xlp : xhp) + (rowBase + row) * 256 + cc * 8;
        __builtin_amdgcn_global_load_lds((const AS1 void*)src,
                                         (AS3 void*)((char*)&As[0] + slot * 16), 16, 0, 0);
    }
    if (tid < 32) { rowmaxU[tid] = 0u; ccnt[tid] = 0; }

    float ns1v[8];   // rows fixed per lane: rt*16 + q*4 + rg
#pragma unroll
    for (int rt = 0; rt < 2; ++rt)
#pragma unroll
        for (int rg = 0; rg < 4; ++rg)
            ns1v[rt * 4 + rg] = ns1[rowBase + rt * 16 + q * 4 + rg];

    __syncthreads();

    for (int ch = 0; ch < 64; ++ch) {
        const int kb = ch * 256;
        f32x4 acc[2][4];
#pragma unroll
        for (int rt = 0; rt < 2; ++rt)
#pragma unroll
            for (int ct = 0; ct < 4; ++ct) acc[rt][ct] = (f32x4){0.f, 0.f, 0.f, 0.f};

        for (int cs = 0; cs < 8; ++cs) {
            __syncthreads();                           // prior Bs reads done
#pragma unroll
            for (int i = 0; i < 8; ++i) {
                const int slot = i * 256 + tid;
                const int half = slot >> 10, code = (slot >> 2) & 255;
                const int qq = (slot & 3) ^ ((code >> 1) & 3);   // bank swizzle
                const unsigned short* src = (half ? wlp : whp)
                    + (kb + code) * 256 + cs * 32 + qq * 8;
                __builtin_amdgcn_global_load_lds((const AS1 void*)src,
                    (AS3 void*)((char*)&Bs[0] + slot * 16), 16, 0, 0);
            }
            __syncthreads();                           // staged (vmcnt drained)

            bf16x8 bh[4], bl[4];
#pragma unroll
            for (int ct = 0; ct < 4; ++ct) {
                const int codeL = w * 64 + ct * 16 + nn;
                const int qp = q ^ ((codeL >> 1) & 3);
                bh[ct] = *(const bf16x8*)&Bs[(codeL * 4 + qp) * 8];
                bl[ct] = *(const bf16x8*)&Bs[(1024 + codeL * 4 + qp) * 8];
            }
#pragma unroll
            for (int rt = 0; rt < 2; ++rt) {
                const int as = (cs * 4 + q) * 32 + rt * 16 + nn;
                const bf16x8 ah = *(const bf16x8*)&As[as * 8];
                const bf16x8 al = *(const bf16x8*)&As[(1024 + as) * 8];
#pragma unroll
                for (int ct = 0; ct < 4; ++ct) {
                    acc[rt][ct] = __builtin_amdgcn_mfma_f32_16x16x32_bf16(ah, bh[ct], acc[rt][ct], 0, 0, 0);
                    acc[rt][ct] = __builtin_amdgcn_mfma_f32_16x16x32_bf16(ah, bl[ct], acc[rt][ct], 0, 0, 0);
                    acc[rt][ct] = __builtin_amdgcn_mfma_f32_16x16x32_bf16(al, bh[ct], acc[rt][ct], 0, 0, 0);
                }
            }
        }

        // ---- fold: approx d, shared row-max, candidate collection ----
        float wnv[4];
#pragma unroll
        for (int ct = 0; ct < 4; ++ct) wnv[ct] = wn[kb + w * 64 + ct * 16 + nn];
        float d[2][4][4];
        float rmax[8];
#pragma unroll
        for (int r8 = 0; r8 < 8; ++r8) rmax[r8] = -3.0e38f;
#pragma unroll
        for (int rt = 0; rt < 2; ++rt)
#pragma unroll
            for (int ct = 0; ct < 4; ++ct)
#pragma unroll
                for (int rg = 0; rg < 4; ++rg) {
                    const float dv = __builtin_fmaf(2.0f, acc[rt][ct][rg],
                                                    ns1v[rt * 4 + rg] - wnv[ct]);
                    d[rt][ct][rg] = dv;
                    rmax[rt * 4 + rg] = fmaxf(rmax[rt * 4 + rg], dv);
                }
#pragma unroll
        for (int r8 = 0; r8 < 8; ++r8) {
            float m = rmax[r8];
            m = fmaxf(m, __shfl_xor(m, 1, 64));
            m = fmaxf(m, __shfl_xor(m, 2, 64));
            m = fmaxf(m, __shfl_xor(m, 4, 64));
            m = fmaxf(m, __shfl_xor(m, 8, 64));
            rmax[r8] = m;
        }
        if (nn == 0) {
#pragma unroll
            for (int rt = 0; rt < 2; ++rt)
#pragma unroll
                for (int rg = 0; rg < 4; ++rg)
                    atomicMax(&rowmaxU[rt * 16 + q * 4 + rg], monof(rmax[rt * 4 + rg]));
        }
        __syncthreads();
        float th[8];
#pragma unroll
        for (int rt = 0; rt < 2; ++rt)
#pragma unroll
            for (int rg = 0; rg < 4; ++rg)
                th[rt * 4 + rg] = unmonof(rowmaxU[rt * 16 + q * 4 + rg]) - MARGIN;
#pragma unroll
        for (int rt = 0; rt < 2; ++rt)
#pragma unroll
            for (int ct = 0; ct < 4; ++ct)
#pragma unroll
                for (int rg = 0; rg < 4; ++rg)
                    if (d[rt][ct][rg] >= th[rt * 4 + rg]) {
                        const int row = rt * 16 + q * 4 + rg;
                        const int pos = atomicAdd(&ccnt[row], 1);
                        if (pos < CAP) ck[row][pos] = (unsigned short)(kb + w * 64 + ct * 16 + nn);
                    }
        // next iteration's leading __syncthreads orders collection vs restage
    }
    __syncthreads();
    if (tid < 32) candc[rowBase + tid] = ccnt[tid];
#pragma unroll
    for (int i = 0; i < 2; ++i) {
        const int e = i * 256 + tid;    // 512 entries
        candk[(rowBase + (e >> 4)) * CAP + (e & 15)] = ck[e >> 4][e & 15];
    }
}

// ---------- K3: exact rescore — 256-thread blocks, wave per 4 rows ----------
// r8/r9 lesson: 16384 single-wave workgroups hit a fixed ~79 ns/wg floor
// (1.3 ms at 1.5% occupancy regardless of internal work). Same bit-identical
// per-candidate chain as r9 (validated absmax 2.4e-7), repackaged as 1024
// blocks x 4 waves x 4 rows.
__global__ __launch_bounds__(256) void k3_rescore(
    const float* __restrict__ xt, const float* __restrict__ weight,
    const float* __restrict__ wn, const float* __restrict__ ns1,
    const unsigned short* __restrict__ candk, const int* __restrict__ candc,
    int* __restrict__ idx)
{
    __shared__ float xsh[4][256];    // per-wave fallback buffer
    const int w = threadIdx.x >> 6, lane = threadIdx.x & 63;
    const int waveId = blockIdx.x * 4 + w;        // 0..4095
#pragma unroll
    for (int rr = 0; rr < 4; ++rr) {
        const int n = waveId * 4 + rr;
        const float4 xv = ((const float4*)(xt + n * 256))[lane];
        const int cnt = candc[n];
        const float nsv = ns1[n];
        float bestd = -3.0e38f; int bestk = 0x7fffffff;
        if (cnt <= CAP) {
            for (int i = 0; i < cnt; ++i) {
                const int k = candk[n * CAP + i];
                const float4 wv = ((const float4*)(weight + k * 256))[lane];
                float p = __fmul_rn(xv.x, wv.x);
                p = __builtin_fmaf(xv.y, wv.y, p);
                p = __builtin_fmaf(xv.z, wv.z, p);
                p = __builtin_fmaf(xv.w, wv.w, p);
#pragma unroll
                for (int off = 1; off < 64; off <<= 1) p += __shfl_xor(p, off, 64);
                const float t1 = __fadd_rn(nsv, -wn[k]);
                const float dd = __fadd_rn(t1, __fmul_rn(2.0f, p));
                if (dd > bestd || (dd == bestd && k < bestk)) { bestd = dd; bestk = k; }
            }
        } else {              // overflow fallback (P ~ 1e-4/row): per-lane strided scan
            ((float4*)xsh[w])[lane] = xv;      // wave-synchronous LDS fill
            const float* xs = xsh[w];
            for (int k = lane; k < KCODES; k += 64) {
                const float* wr = weight + k * 256;
                float m = 0.f;
                for (int c = 0; c < 256; ++c) m = __builtin_fmaf(xs[c], wr[c], m);
                const float t1 = __fadd_rn(nsv, -wn[k]);
                const float dd = __fadd_rn(t1, __fmul_rn(2.0f, m));
                if (dd > bestd || (dd == bestd && k < bestk)) { bestd = dd; bestk = k; }
            }
#pragma unroll
            for (int off = 1; off < 64; off <<= 1) {
                const float od = __shfl_xor(bestd, off, 64);
                const int   ok = __shfl_xor(bestk, off, 64);
                if (od > bestd || (od == bestd && ok < bestk)) { bestd = od; bestk = ok; }
            }
        }
        if (lane == 0) idx[n] = bestk;
    }
}

// ---------- K5: gather outputs + loss partials ----------
__global__ void k5_out(const float* __restrict__ xt, const float* __restrict__ weight,
                       const float* __restrict__ mask, const int* __restrict__ idx,
                       float* __restrict__ out, float* __restrict__ sums)
{
    __shared__ float red[4];
    const int n = blockIdx.x, c = threadIdx.x;
    const int id = idx[n];
    const float mval = mask[n];
    const float wq = weight[id * 256 + c];
    const float xv = xt[n * 256 + c];
    const int b = n >> 10, hw = n & 1023;
    out[(b * 256 + c) * 1024 + hw] = wq;
    float e = wq - xv;
    float v = mval * e * e;
    for (int o = 32; o > 0; o >>= 1) v += __shfl_down(v, o, 64);
    if ((c & 63) == 0) red[c >> 6] = v;
    __syncthreads();
    if (c == 0) {
        atomicAdd(&sums[1], red[0] + red[1] + red[2] + red[3]);
        atomicAdd(&sums[0], mval);
        out[OUT_IND + n] = (float)id;
    }
}

// ---------- K6: finalize loss ----------
__global__ void k6_final(const float* __restrict__ sums, float* __restrict__ out)
{
    if (threadIdx.x == 0)
        out[OUT_LOSS] = (float)(1.25 * (double)sums[1] / (256.0 * (double)sums[0]));
}

extern "C" void kernel_launch(void* const* d_in, const int* in_sizes, int n_in,
                              void* d_out, int out_size, void* d_ws, size_t ws_size,
                              hipStream_t stream)
{
    const float* x      = (const float*)d_in[0];   // [16,256,32,32]
    const float* mask   = (const float*)d_in[1];   // [16,1,32,32]
    const float* weight = (const float*)d_in[2];   // [16384,256]
    float* out = (float*)d_out;
    float* ws  = (float*)d_ws;

    float* xt  = ws + OFF_XT;
    unsigned short* xhp = (unsigned short*)(ws + OFF_XHP);
    unsigned short* xlp = (unsigned short*)(ws + OFF_XLP);
    unsigned short* whp = (unsigned short*)(ws + OFF_WHP);
    unsigned short* wlp = (unsigned short*)(ws + OFF_WLP);
    float* wn   = ws + OFF_WN;
    float* ns1  = ws + OFF_NS1;
    int*   idx  = (int*)(ws + OFF_IDX);
    unsigned short* candk = (unsigned short*)(ws + OFF_CAND);
    int*   candc = (int*)(ws + OFF_CCNT);
    float* sums = ws + OFF_SUMS;

    hipMemsetAsync(sums, 0, 2 * sizeof(float), stream);
    k1a_pack_x<<<dim3(32, 8, 16), dim3(32, 8), 0, stream>>>(x, xt);
    k_rownorm<<<512, 256, 0, stream>>>((const float4*)xt, ns1, -1.0f);
    k_rownorm<<<512, 256, 0, stream>>>((const float4*)weight, wn, 1.0f);
    k_split<<<4096, 256, 0, stream>>>((const float4*)xt, (ushort4*)xhp, (ushort4*)xlp);
    k_split<<<4096, 256, 0, stream>>>((const float4*)weight, (ushort4*)whp, (ushort4*)wlp);
    k2_mfma<<<512, 256, 0, stream>>>(xhp, xlp, whp, wlp, wn, ns1, candk, candc);
    k3_rescore<<<1024, 256, 0, stream>>>(xt, weight, wn, ns1, candk, candc, idx);
    k5_out<<<16384, 256, 0, stream>>>(xt, weight, mask, idx, out, sums);
    k6_final<<<1, 64, 0, stream>>>(sums, out);
}

// Round 11
// 1203.153 us; speedup vs baseline: 2.0895x; 2.0895x over previous
//
#include <hip/hip_runtime.h>

// Problem: B,C,H,W = 16,256,32,32; K=16384. N = 16384 rows.
#define KCODES 16384
#define NPOS   16384
#define CAP    64      // r10: CAP=16 overflowed on ~4 rows -> 1.3ms serial fallback tail
#define MARGIN 1e-4f   // >= 2*(grid-rounding 1.53e-5 + split-bf16 err ~3e-7); cushion 1.6x

// ws float offsets (total ~52.7 MB)
#define OFF_XT    0           // [N][256] fp32 packed x ("flat")
#define OFF_XHP   4194304     // bf16 plane xh [N][256]
#define OFF_XLP   6291456     // bf16 plane xl
#define OFF_WHP   8388608     // bf16 plane wh [K][256]
#define OFF_WLP   10485760    // bf16 plane wl
#define OFF_WN    12582912    // [K]  |w|^2 (np-pairwise exact)
#define OFF_NS1   12599296    // [N] -|f|^2
#define OFF_IDX   12615680    // [N] final argmax (int)
#define OFF_CAND  12632064    // u16 [N][64] candidate codes (524288 floats)
#define OFF_CCNT  13156352    // [N] candidate counts (int)
#define OFF_SUMS  13172736    // [2] {sum mask, sum masked err^2}

#define OUT_LOSS  4194304
#define OUT_IND   4194305

#define AS1 __attribute__((address_space(1)))
#define AS3 __attribute__((address_space(3)))

typedef short bf16x8 __attribute__((ext_vector_type(8)));   // 8 bf16 = 4 VGPRs
typedef float f32x4  __attribute__((ext_vector_type(4)));

__device__ inline unsigned short bf16rn(float f) {
    unsigned u = __float_as_uint(f);
    return (unsigned short)((u + 0x7FFFu + ((u >> 16) & 1u)) >> 16);
}
__device__ inline float bf2f(unsigned short h) {
    return __uint_as_float(((unsigned)h) << 16);
}
__device__ inline unsigned monof(float f) {   // monotone float->uint key
    unsigned u = __float_as_uint(f);
    return (u & 0x80000000u) ? ~u : (u | 0x80000000u);
}
__device__ inline float unmonof(unsigned k) {
    unsigned u = (k & 0x80000000u) ? (k & 0x7fffffffu) : ~k;
    return __uint_as_float(u);
}

// ---------- K1a: pack x (B,C,HW) -> xt[N][256] via LDS tile transpose ----------
__global__ void k1a_pack_x(const float* __restrict__ x, float* __restrict__ xt)
{
    __shared__ float t[32][33];
    const int p0 = blockIdx.x * 32, c0 = blockIdx.y * 32, b = blockIdx.z;
    const int tx = threadIdx.x, ty = threadIdx.y;   // 32 x 8
#pragma unroll
    for (int i = 0; i < 4; ++i) {
        int cl = ty + i * 8;
        t[cl][tx] = x[(b * 256 + c0 + cl) * 1024 + p0 + tx];
    }
    __syncthreads();
#pragma unroll
    for (int i = 0; i < 4; ++i) {
        int pl = ty + i * 8;
        xt[(b * 1024 + p0 + pl) * 256 + c0 + tx] = t[tx][pl];
    }
}

// ---------- Ksplit: fp32 row-major -> (bf16 hi plane, bf16 lo plane) ----------
__global__ void k_split(const float4* __restrict__ src4,
                        ushort4* __restrict__ hp, ushort4* __restrict__ lp)
{
    const int i = blockIdx.x * 256 + threadIdx.x;
    const float4 v = src4[i];
    ushort4 h, l;
    h.x = bf16rn(v.x); l.x = bf16rn(v.x - bf2f(h.x));
    h.y = bf16rn(v.y); l.y = bf16rn(v.y - bf2f(h.y));
    h.z = bf16rn(v.z); l.z = bf16rn(v.z - bf2f(h.z));
    h.w = bf16rn(v.w); l.w = bf16rn(v.w - bf2f(h.w));
    hp[i] = h; lp[i] = l;
}

// ---------- Krn: numpy-pairwise fp32 sum of squares per 256-elem row ----------
__global__ void k_rownorm(const float4* __restrict__ src4, float* __restrict__ out,
                          float sign)
{
    __shared__ float4 rows[32 * 64];
    const int tid = threadIdx.x;
    const int r0 = blockIdx.x * 32;
#pragma unroll
    for (int i = 0; i < 8; ++i) rows[tid + 256 * i] = src4[r0 * 64 + tid + 256 * i];
    __syncthreads();
    const int rl = tid >> 3, j = tid & 7;
    const float* qp = (const float*)&rows[rl * 64];
    float h[2];
#pragma unroll
    for (int half = 0; half < 2; ++half) {
        const float* p = qp + half * 128;
        float x = p[j];
        float r = __fmul_rn(x, x);
#pragma unroll
        for (int i = 1; i < 16; ++i) {
            float y = p[8 * i + j];
            r = __fadd_rn(r, __fmul_rn(y, y));
        }
        float t = __fadd_rn(r, __shfl_xor(r, 1));
        t = __fadd_rn(t, __shfl_xor(t, 2));
        t = __fadd_rn(t, __shfl_xor(t, 4));
        h[half] = t;
    }
    if (j == 0) out[r0 + rl] = sign * __fadd_rn(h[0], h[1]);
}

// ---------- K2: split-bf16 MFMA GEMM + approx-d argmax candidate collection ----
__global__ __launch_bounds__(256, 2) void k2_mfma(
    const unsigned short* __restrict__ xhp, const unsigned short* __restrict__ xlp,
    const unsigned short* __restrict__ whp, const unsigned short* __restrict__ wlp,
    const float* __restrict__ wn, const float* __restrict__ ns1,
    unsigned short* __restrict__ candk, int* __restrict__ candc)
{
    __shared__ __align__(16) unsigned short As[16384]; // 32KB: slot16 = half*1024 + cc*32 + row
    __shared__ __align__(16) unsigned short Bs[16384]; // 32KB: slot16 = half*1024 + code*4 + q'
    __shared__ unsigned rowmaxU[32];
    __shared__ int ccnt[32];
    __shared__ unsigned short ck[32][CAP];             // 4 KB

    const int tid  = threadIdx.x;
    const int lane = tid & 63;
    const int w    = tid >> 6;     // wave 0..3 -> code sub-range
    const int q    = lane >> 4;    // k-chunk quad
    const int nn   = lane & 15;    // A-row / B-col / D-col position
    const int rowBase = blockIdx.x * 32;

    // stage A once: 2048 slots of 16B
#pragma unroll
    for (int i = 0; i < 8; ++i) {
        const int slot = i * 256 + tid;
        const int half = slot >> 10, cc = (slot >> 5) & 31, row = slot & 31;
        const unsigned short* src = (half ? xlp : xhp) + (rowBase + row) * 256 + cc * 8;
        __builtin_amdgcn_global_load_lds((const AS1 void*)src,
                                         (AS3 void*)((char*)&As[0] + slot * 16), 16, 0, 0);
    }
    if (tid < 32) { rowmaxU[tid] = 0u; ccnt[tid] = 0; }

    float ns1v[8];   // rows fixed per lane: rt*16 + q*4 + rg
#pragma unroll
    for (int rt = 0; rt < 2; ++rt)
#pragma unroll
        for (int rg = 0; rg < 4; ++rg)
            ns1v[rt * 4 + rg] = ns1[rowBase + rt * 16 + q * 4 + rg];

    __syncthreads();

    for (int ch = 0; ch < 64; ++ch) {
        const int kb = ch * 256;
        f32x4 acc[2][4];
#pragma unroll
        for (int rt = 0; rt < 2; ++rt)
#pragma unroll
            for (int ct = 0; ct < 4; ++ct) acc[rt][ct] = (f32x4){0.f, 0.f, 0.f, 0.f};

        for (int cs = 0; cs < 8; ++cs) {
            __syncthreads();                           // prior Bs reads done
#pragma unroll
            for (int i = 0; i < 8; ++i) {
                const int slot = i * 256 + tid;
                const int half = slot >> 10, code = (slot >> 2) & 255;
                const int qq = (slot & 3) ^ ((code >> 1) & 3);   // bank swizzle
                const unsigned short* src = (half ? wlp : whp)
                    + (kb + code) * 256 + cs * 32 + qq * 8;
                __builtin_amdgcn_global_load_lds((const AS1 void*)src,
                    (AS3 void*)((char*)&Bs[0] + slot * 16), 16, 0, 0);
            }
            __syncthreads();                           // staged (vmcnt drained)

            bf16x8 bh[4], bl[4];
#pragma unroll
            for (int ct = 0; ct < 4; ++ct) {
                const int codeL = w * 64 + ct * 16 + nn;
                const int qp = q ^ ((codeL >> 1) & 3);
                bh[ct] = *(const bf16x8*)&Bs[(codeL * 4 + qp) * 8];
                bl[ct] = *(const bf16x8*)&Bs[(1024 + codeL * 4 + qp) * 8];
            }
#pragma unroll
            for (int rt = 0; rt < 2; ++rt) {
                const int as = (cs * 4 + q) * 32 + rt * 16 + nn;
                const bf16x8 ah = *(const bf16x8*)&As[as * 8];
                const bf16x8 al = *(const bf16x8*)&As[(1024 + as) * 8];
#pragma unroll
                for (int ct = 0; ct < 4; ++ct) {
                    acc[rt][ct] = __builtin_amdgcn_mfma_f32_16x16x32_bf16(ah, bh[ct], acc[rt][ct], 0, 0, 0);
                    acc[rt][ct] = __builtin_amdgcn_mfma_f32_16x16x32_bf16(ah, bl[ct], acc[rt][ct], 0, 0, 0);
                    acc[rt][ct] = __builtin_amdgcn_mfma_f32_16x16x32_bf16(al, bh[ct], acc[rt][ct], 0, 0, 0);
                }
            }
        }

        // ---- fold: approx d, shared row-max, candidate collection ----
        float wnv[4];
#pragma unroll
        for (int ct = 0; ct < 4; ++ct) wnv[ct] = wn[kb + w * 64 + ct * 16 + nn];
        float d[2][4][4];
        float rmax[8];
#pragma unroll
        for (int r8 = 0; r8 < 8; ++r8) rmax[r8] = -3.0e38f;
#pragma unroll
        for (int rt = 0; rt < 2; ++rt)
#pragma unroll
            for (int ct = 0; ct < 4; ++ct)
#pragma unroll
                for (int rg = 0; rg < 4; ++rg) {
                    const float dv = __builtin_fmaf(2.0f, acc[rt][ct][rg],
                                                    ns1v[rt * 4 + rg] - wnv[ct]);
                    d[rt][ct][rg] = dv;
                    rmax[rt * 4 + rg] = fmaxf(rmax[rt * 4 + rg], dv);
                }
#pragma unroll
        for (int r8 = 0; r8 < 8; ++r8) {
            float m = rmax[r8];
            m = fmaxf(m, __shfl_xor(m, 1, 64));
            m = fmaxf(m, __shfl_xor(m, 2, 64));
            m = fmaxf(m, __shfl_xor(m, 4, 64));
            m = fmaxf(m, __shfl_xor(m, 8, 64));
            rmax[r8] = m;
        }
        if (nn == 0) {
#pragma unroll
            for (int rt = 0; rt < 2; ++rt)
#pragma unroll
                for (int rg = 0; rg < 4; ++rg)
                    atomicMax(&rowmaxU[rt * 16 + q * 4 + rg], monof(rmax[rt * 4 + rg]));
        }
        __syncthreads();
        float th[8];
#pragma unroll
        for (int rt = 0; rt < 2; ++rt)
#pragma unroll
            for (int rg = 0; rg < 4; ++rg)
                th[rt * 4 + rg] = unmonof(rowmaxU[rt * 16 + q * 4 + rg]) - MARGIN;
#pragma unroll
        for (int rt = 0; rt < 2; ++rt)
#pragma unroll
            for (int ct = 0; ct < 4; ++ct)
#pragma unroll
                for (int rg = 0; rg < 4; ++rg)
                    if (d[rt][ct][rg] >= th[rt * 4 + rg]) {
                        const int row = rt * 16 + q * 4 + rg;
                        const int pos = atomicAdd(&ccnt[row], 1);
                        if (pos < CAP) ck[row][pos] = (unsigned short)(kb + w * 64 + ct * 16 + nn);
                    }
        // next iteration's leading __syncthreads orders collection vs restage
    }
    __syncthreads();
    if (tid < 32) candc[rowBase + tid] = ccnt[tid];
#pragma unroll
    for (int i = 0; i < 8; ++i) {
        const int e = i * 256 + tid;    // 2048 entries = 32 rows x CAP(64)
        candk[(rowBase + (e >> 6)) * CAP + (e & 63)] = ck[e >> 6][e & 63];
    }
}

// ---------- K3: exact rescore — 256-thr blocks, wave per 4 rows, coalesced ----
// r10 post-mortem: 1.3ms was CAP-overflow stragglers (~4 rows) running a serial
// scalar full scan. CAP=64 makes overflow P~1e-14; fallback below is now
// wave-coalesced (same chain as candidate path over all 16K codes) as pure
// defense-in-depth.
__global__ __launch_bounds__(256) void k3_rescore(
    const float* __restrict__ xt, const float* __restrict__ weight,
    const float* __restrict__ wn, const float* __restrict__ ns1,
    const unsigned short* __restrict__ candk, const int* __restrict__ candc,
    int* __restrict__ idx)
{
    const int w = threadIdx.x >> 6, lane = threadIdx.x & 63;
    const int waveId = blockIdx.x * 4 + w;        // 0..4095
#pragma unroll
    for (int rr = 0; rr < 4; ++rr) {
        const int n = waveId * 4 + rr;
        const float4 xv = ((const float4*)(xt + n * 256))[lane];
        const int cnt = candc[n];
        const float nsv = ns1[n];
        float bestd = -3.0e38f; int bestk = 0x7fffffff;
        if (cnt <= CAP) {
            for (int i = 0; i < cnt; ++i) {
                const int k = candk[n * CAP + i];
                const float4 wv = ((const float4*)(weight + k * 256))[lane];
                float p = __fmul_rn(xv.x, wv.x);
                p = __builtin_fmaf(xv.y, wv.y, p);
                p = __builtin_fmaf(xv.z, wv.z, p);
                p = __builtin_fmaf(xv.w, wv.w, p);
#pragma unroll
                for (int off = 1; off < 64; off <<= 1) p += __shfl_xor(p, off, 64);
                const float t1 = __fadd_rn(nsv, -wn[k]);
                const float dd = __fadd_rn(t1, __fmul_rn(2.0f, p));
                if (dd > bestd || (dd == bestd && k < bestk)) { bestd = dd; bestk = k; }
            }
        } else {              // overflow fallback: exact full scan, wave-coalesced
            for (int k = 0; k < KCODES; ++k) {
                const float4 wv = ((const float4*)(weight + k * 256))[lane];
                float p = __fmul_rn(xv.x, wv.x);
                p = __builtin_fmaf(xv.y, wv.y, p);
                p = __builtin_fmaf(xv.z, wv.z, p);
                p = __builtin_fmaf(xv.w, wv.w, p);
#pragma unroll
                for (int off = 1; off < 64; off <<= 1) p += __shfl_xor(p, off, 64);
                const float t1 = __fadd_rn(nsv, -wn[k]);
                const float dd = __fadd_rn(t1, __fmul_rn(2.0f, p));
                if (dd > bestd) { bestd = dd; bestk = k; }   // ascending k: first-wins
            }
        }
        if (lane == 0) idx[n] = bestk;
    }
}

// ---------- K5: gather outputs + loss partials ----------
__global__ void k5_out(const float* __restrict__ xt, const float* __restrict__ weight,
                       const float* __restrict__ mask, const int* __restrict__ idx,
                       float* __restrict__ out, float* __restrict__ sums)
{
    __shared__ float red[4];
    const int n = blockIdx.x, c = threadIdx.x;
    const int id = idx[n];
    const float mval = mask[n];
    const float wq = weight[id * 256 + c];
    const float xv = xt[n * 256 + c];
    const int b = n >> 10, hw = n & 1023;
    out[(b * 256 + c) * 1024 + hw] = wq;
    float e = wq - xv;
    float v = mval * e * e;
    for (int o = 32; o > 0; o >>= 1) v += __shfl_down(v, o, 64);
    if ((c & 63) == 0) red[c >> 6] = v;
    __syncthreads();
    if (c == 0) {
        atomicAdd(&sums[1], red[0] + red[1] + red[2] + red[3]);
        atomicAdd(&sums[0], mval);
        out[OUT_IND + n] = (float)id;
    }
}

// ---------- K6: finalize loss ----------
__global__ void k6_final(const float* __restrict__ sums, float* __restrict__ out)
{
    if (threadIdx.x == 0)
        out[OUT_LOSS] = (float)(1.25 * (double)sums[1] / (256.0 * (double)sums[0]));
}

extern "C" void kernel_launch(void* const* d_in, const int* in_sizes, int n_in,
                              void* d_out, int out_size, void* d_ws, size_t ws_size,
                              hipStream_t stream)
{
    const float* x      = (const float*)d_in[0];   // [16,256,32,32]
    const float* mask   = (const float*)d_in[1];   // [16,1,32,32]
    const float* weight = (const float*)d_in[2];   // [16384,256]
    float* out = (float*)d_out;
    float* ws  = (float*)d_ws;

    float* xt  = ws + OFF_XT;
    unsigned short* xhp = (unsigned short*)(ws + OFF_XHP);
    unsigned short* xlp = (unsigned short*)(ws + OFF_XLP);
    unsigned short* whp = (unsigned short*)(ws + OFF_WHP);
    unsigned short* wlp = (unsigned short*)(ws + OFF_WLP);
    float* wn   = ws + OFF_WN;
    float* ns1  = ws + OFF_NS1;
    int*   idx  = (int*)(ws + OFF_IDX);
    unsigned short* candk = (unsigned short*)(ws + OFF_CAND);
    int*   candc = (int*)(ws + OFF_CCNT);
    float* sums = ws + OFF_SUMS;

    hipMemsetAsync(sums, 0, 2 * sizeof(float), stream);
    k1a_pack_x<<<dim3(32, 8, 16), dim3(32, 8), 0, stream>>>(x, xt);
    k_rownorm<<<512, 256, 0, stream>>>((const float4*)xt, ns1, -1.0f);
    k_rownorm<<<512, 256, 0, stream>>>((const float4*)weight, wn, 1.0f);
    k_split<<<4096, 256, 0, stream>>>((const float4*)xt, (ushort4*)xhp, (ushort4*)xlp);
    k_split<<<4096, 256, 0, stream>>>((const float4*)weight, (ushort4*)whp, (ushort4*)wlp);
    k2_mfma<<<512, 256, 0, stream>>>(xhp, xlp, whp, wlp, wn, ns1, candk, candc);
    k3_rescore<<<1024, 256, 0, stream>>>(xt, weight, wn, ns1, candk, candc, idx);
    k5_out<<<16384, 256, 0, stream>>>(xt, weight, mask, idx, out, sums);
    k6_final<<<1, 64, 0, stream>>>(sums, out);
}